// Round 1
// 115.419 us; speedup vs baseline: 1.0633x; 1.0633x over previous
//
#include <hip/hip_runtime.h>

#define KSZ   121
#define KMEAN 60
#define IMW   512
#define IMH   512
#define NPLANES 24            // 8 * 3
#define NROWS (NPLANES * IMH) // 12288 independent image rows

typedef float    f32x4 __attribute__((ext_vector_type(4)));
typedef float    f32x2 __attribute__((ext_vector_type(2)));
typedef int      i32x4 __attribute__((ext_vector_type(4)));
typedef _Float16 f16x8 __attribute__((ext_vector_type(8)));
typedef _Float16 f16x2 __attribute__((ext_vector_type(2)));

// CK-style raw buffer intrinsics: HW bounds check returns 0 for OOB lanes.
__device__ unsigned buf_load_u32(i32x4 srsrc, int voffset, int soffset, int aux)
    __asm("llvm.amdgcn.raw.buffer.load.i32");
__device__ void buf_store_x2(f32x2 data, i32x4 srsrc, int voffset, int soffset, int aux)
    __asm("llvm.amdgcn.raw.buffer.store.v2f32");

// NOTE: SRD lives in SGPRs -> every input to make_srd MUST be wave-uniform.
__device__ __forceinline__ i32x4 make_srd(const void* p, int bytes) {
    union { const void* p; unsigned u[2]; } a; a.p = p;
    i32x4 r;
    r.x = (int)__builtin_amdgcn_readfirstlane((int)a.u[0]);   // wave-uniform base
    r.y = (int)__builtin_amdgcn_readfirstlane((int)a.u[1]);
    r.z = bytes;          // num_records: OOB load -> 0, OOB store -> dropped
    r.w = 0x00020000;     // raw dword SRD word3 (gfx9/gfx950)
    return r;
}

// unpack dword (2x fp16) -> 2 fp32
__device__ __forceinline__ f32x2 f16unpk(unsigned u) {
    union { unsigned u; f16x2 h; } cv; cv.u = u;
    f32x2 r; r.x = (float)cv.h.x; r.y = (float)cv.h.y;
    return r;
}

// ---------------------------------------------------------------------------
// ws layout (bytes):
//   [    0,  512)  taps w[0..120] fp32 (pad to 128 with 0)
//   [  512, 2560)  L[512] fp32   (float idx 128..640)
//   [ 2560, 4608)  R[512] fp32   (float idx 640..1152)
//   [ 4608,14848)  10 MFMA weight-band tables, fp16, fragment order:
//                    T[tt][lane][j], tt = tau+1, tau in [-1,8]
//                    value = w[16*tau + kk - ci - 4], kk = 8*(lane>>4)+j,
//                    ci = lane&15; 0 outside [0,120].
//   [16384, ... )  fp16 tmp (h-blurred), 24 planes * 512*512 * 2B
//
// Banded-matmul identity (both passes share the tables):
//   pass out-subtile index n (16 wide), K-step s (32 wide, window start -64):
//   w-index = 16*(2s-n) + kk - idx - 4  ->  table tau = 2s-n.
// ---------------------------------------------------------------------------
__global__ __launch_bounds__(128) void weights_kernel(const float* __restrict__ sigma,
                                                      float* __restrict__ ws) {
    __shared__ float w[121];
    __shared__ float P[121];
    int t = threadIdx.x;
    float s = sigma[0] * 8.0f + 16.0f;
    float ninv = -1.0f / (2.0f * s * s);
    if (t < 121) { float d = (float)(t - KMEAN); w[t] = __expf(d * d * ninv); }
    __syncthreads();
    if (t == 0) {
        float sum = 0.f;
        for (int i = 0; i < 121; ++i) sum += w[i];
        float inv = 1.f / sum, run = 0.f;
        for (int i = 0; i < 121; ++i) { float wi = w[i] * inv; w[i] = wi; run += wi; P[i] = run; }
    }
    __syncthreads();
    ws[t] = (t < 121) ? w[t] : 0.f;                       // taps, 121..127 = 0
    #pragma unroll
    for (int j = 0; j < 4; ++j) {
        int o = t * 4 + j;
        ws[128 + o] = (o <= 59)  ? P[59 - o]          : 0.f;   // L
        ws[640 + o] = (o >= 452) ? (1.f - P[571 - o]) : 0.f;   // R
    }
    // MFMA band tables (fp16, fragment order). 10 tables x 512 entries.
    _Float16* tab = (_Float16*)((char*)ws + 4608);
    #pragma unroll
    for (int tt = 0; tt < 10; ++tt) {
        for (int e = t; e < 512; e += 128) {
            int lane = e >> 3, j = e & 7;
            int kk = ((lane >> 4) << 3) + j;   // slot->k convention (shared A/B)
            int ci = lane & 15;
            int wi = 16 * (tt - 1) + kk - ci - 4;
            float v = (wi >= 0 && wi <= 120) ? w[wi] : 0.f;
            tab[tt * 512 + e] = (_Float16)v;
        }
    }
}

// ---------------------------------------------------------------------------
// Kernel 2: horizontal pass as banded f16 MFMA (matrix pipe, was fp32 VALU).
//   tmp[r, c] = sum_k x[r, k] * w[k - c + 60]  (zero-pad; replicate restored
//   by x0*L[c] + xN*R[c] corrections on the two edge col-tiles).
// Wave tile: 32 rows (q=0,1) x 64 cols (n=0..3). Block = 4 waves = 128 rows.
// K-window = [c0-64, c0+128), 6 steps of 32; steps fully outside [0,512)
// are skipped (32-aligned -> all-in or all-out == zero-pad semantics).
// B operand = wave-uniform band tables T[2s-n]; A = x rows, fp32->fp16 cvt.
// Layout invariance: A and B fragments both use slot k = 8*(lane>>4)+j, so
// the contraction is correct for any (symmetric) HW k-order.
// ---------------------------------------------------------------------------
__global__ __launch_bounds__(256) void hblur_mfma(const float* __restrict__ x,
                                                  const float* __restrict__ ws,
                                                  unsigned short* __restrict__ tmpb) {
    // XCD-aware swizzle: 768 blocks % 8 == 0; consecutive swz share x-windows.
    const int bid = blockIdx.x;
    const int swz = (bid & 7) * 96 + (bid >> 3);
    const int br = swz >> 3;                 // 0..95  row-block
    const int bc = swz & 7;                  // 0..7   col-tile
    const int tid  = threadIdx.x;
    const int lane = tid & 63;
    const int g    = lane >> 4;              // k-block / D-row group
    const int ci   = lane & 15;              // A row within tile / D col
    const int R0   = br * 128 + (tid >> 6) * 32;
    const int c0   = bc * 64;

    // preload the 10 band tables (wave-uniform B fragments)
    const _Float16* __restrict__ tab = (const _Float16*)((const char*)ws + 4608);
    f16x8 T[10];
    #pragma unroll
    for (int tt = 0; tt < 10; ++tt)
        T[tt] = ((const f16x8*)(tab + tt * 512))[lane];

    f32x4 acc[2][4];
    #pragma unroll
    for (int q = 0; q < 2; ++q)
        #pragma unroll
        for (int n = 0; n < 4; ++n)
            acc[q][n] = (f32x4){0.f, 0.f, 0.f, 0.f};

    const float* __restrict__ xr0 = x + (size_t)(R0 + ci) * IMW;        // q=0 row
    const float* __restrict__ xr1 = x + (size_t)(R0 + 16 + ci) * IMW;   // q=1 row

    #pragma unroll
    for (int s = 0; s < 6; ++s) {
        const int colbase = c0 - 64 + 32 * s;
        if ((unsigned)colbase < 512u) {      // 32-aligned step: all-in or all-out
            const int co = colbase + 8 * g;
            f32x4 u0 = *(const f32x4*)(xr0 + co);
            f32x4 u1 = *(const f32x4*)(xr0 + co + 4);
            f32x4 v0 = *(const f32x4*)(xr1 + co);
            f32x4 v1 = *(const f32x4*)(xr1 + co + 4);
            f16x8 A0, A1;
            A0[0]=(_Float16)u0.x; A0[1]=(_Float16)u0.y; A0[2]=(_Float16)u0.z; A0[3]=(_Float16)u0.w;
            A0[4]=(_Float16)u1.x; A0[5]=(_Float16)u1.y; A0[6]=(_Float16)u1.z; A0[7]=(_Float16)u1.w;
            A1[0]=(_Float16)v0.x; A1[1]=(_Float16)v0.y; A1[2]=(_Float16)v0.z; A1[3]=(_Float16)v0.w;
            A1[4]=(_Float16)v1.x; A1[5]=(_Float16)v1.y; A1[6]=(_Float16)v1.z; A1[7]=(_Float16)v1.w;
            #pragma unroll
            for (int n = 0; n < 4; ++n) {
                const int tt = 2 * s - n + 1;          // tau+1, compile-time
                if (tt >= 0 && tt < 10) {
                    acc[0][n] = __builtin_amdgcn_mfma_f32_16x16x32_f16(A0, T[tt], acc[0][n], 0, 0, 0);
                    acc[1][n] = __builtin_amdgcn_mfma_f32_16x16x32_f16(A1, T[tt], acc[1][n], 0, 0, 0);
                }
            }
        }
    }

    // replicate-pad corrections, only the two edge col-tiles have nonzero L/R
    if (c0 == 0 || c0 == 448) {
        const float* __restrict__ Lf = ws + 128;
        const float* __restrict__ Rf = ws + 640;
        float Lc[4], Rc[4];
        #pragma unroll
        for (int n = 0; n < 4; ++n) {
            Lc[n] = Lf[c0 + 16 * n + ci];
            Rc[n] = Rf[c0 + 16 * n + ci];
        }
        #pragma unroll
        for (int q = 0; q < 2; ++q) {
            #pragma unroll
            for (int r = 0; r < 4; ++r) {
                const int row = R0 + 16 * q + 4 * g + r;   // D row = 4*(lane>>4)+reg
                const float x0 = x[(size_t)row * IMW];
                const float xN = x[(size_t)row * IMW + IMW - 1];
                #pragma unroll
                for (int n = 0; n < 4; ++n)
                    acc[q][n][r] += x0 * Lc[n] + xN * Rc[n];
            }
        }
    }

    // store fp16 tmp: D layout col = lane&15, row = 4*(lane>>4)+reg (m89)
    _Float16* __restrict__ tp = (_Float16*)tmpb;
    #pragma unroll
    for (int q = 0; q < 2; ++q)
        #pragma unroll
        for (int r = 0; r < 4; ++r) {
            const size_t rowoff = (size_t)(R0 + 16 * q + 4 * g + r) * IMW;
            #pragma unroll
            for (int n = 0; n < 4; ++n)
                tp[rowoff + c0 + 16 * n + ci] = (_Float16)acc[q][n][r];
        }
}

// ---------------------------------------------------------------------------
// Kernel 3: vertical pass — round-7 proven body, tmp now fp16 (was bf16).
// Loads are b32 (one fp16 col-pair), unpacked to fp32 (2 v_cvt) into the same
// f32x2 window. SRD: voffL = colpair*4, soffset = row*1024 (SALU); rows
// <0/>511 -> HW zero-fill dword -> unpacks to 0.0 (zero-pad preserved).
// P0/P1 2-chunk prefetch kept. Output stays fp32 (b64 stores).
// ---------------------------------------------------------------------------
#define VR 16
__global__ __launch_bounds__(128) void vblur(const unsigned short* __restrict__ tmpb,
                                             const float* __restrict__ ws,
                                             float* __restrict__ out) {
    const int t     = threadIdx.x;                 // 0..127
    const int b     = blockIdx.x;                  // 0..1535
    const int half  = b & 1;                       // column half
    const int r0    = ((b >> 1) & 31) * VR;        // output rows r0..r0+15
    const int plane = b >> 6;
    const int base  = r0 - KMEAN;
    const int cp    = half * 128 + t;              // col-pair index 0..255
    const int voffL = cp * 4;                      // byte offset in fp16 row
    const int voffS = cp * 8;                      // byte offset in fp32 row

    const unsigned short* __restrict__ tp = tmpb + (size_t)plane * (IMW * IMH);
    float* __restrict__ op = out + (size_t)plane * (IMW * IMH);
    const i32x4 srdT = make_srd(tp, IMW * IMH * 2);   // fp16 plane buffer
    const i32x4 srdO = make_srd(op, IMW * IMH * 4);
    const f32x4* __restrict__ w4 = (const f32x4*)ws;

    f32x2 W[VR + 3];                               // rows base+4c .. base+4c+18
    #pragma unroll
    for (int d = 0; d < VR + 3; ++d)
        W[d] = f16unpk(buf_load_u32(srdT, voffL, (base + d) * (IMW * 2), 0));
    unsigned P0[4], P1[4];                         // chunks c+1, c+2 in flight
    #pragma unroll
    for (int e = 0; e < 4; ++e)
        P0[e] = buf_load_u32(srdT, voffL, (base + 19 + e) * (IMW * 2), 0);
    #pragma unroll
    for (int e = 0; e < 4; ++e)
        P1[e] = buf_load_u32(srdT, voffL, (base + 23 + e) * (IMW * 2), 0);

    f32x2 acc[VR];
    #pragma unroll
    for (int i = 0; i < VR; ++i) { acc[i].x = 0.f; acc[i].y = 0.f; }

    #pragma unroll
    for (int c = 0; c < 31; ++c) {
        f32x4 w = w4[c];                           // uniform -> s_load
        #pragma unroll
        for (int s = 0; s < 4; ++s) {
            float wv = (s == 0) ? w.x : (s == 1) ? w.y : (s == 2) ? w.z : w.w;
            #pragma unroll
            for (int i = 0; i < VR; ++i) {
                acc[i].x = fmaf(wv, W[i + s].x, acc[i].x);
                acc[i].y = fmaf(wv, W[i + s].y, acc[i].y);
            }
        }
        if (c < 30) {
            #pragma unroll
            for (int d = 0; d < VR - 1; ++d) W[d] = W[d + 4];
            #pragma unroll
            for (int e = 0; e < 4; ++e) W[VR - 1 + e] = f16unpk(P0[e]);
            #pragma unroll
            for (int e = 0; e < 4; ++e) P0[e] = P1[e];
            if (c < 28) {
                #pragma unroll
                for (int e = 0; e < 4; ++e)
                    P1[e] = buf_load_u32(srdT, voffL, (base + 4*c + 27 + e) * (IMW * 2), 0);
            }
        }
    }

    // replicate-pad corrections: rows 0 and 511, scalar weights L[r]/R[r]
    f32x2 T0 = f16unpk(buf_load_u32(srdT, voffL, 0, 0));
    f32x2 TN = f16unpk(buf_load_u32(srdT, voffL, (IMH - 1) * (IMW * 2), 0));
    const float* __restrict__ Lf = ws + 128;
    const float* __restrict__ Rf = ws + 640;
    #pragma unroll
    for (int i = 0; i < VR; ++i) {
        float L = Lf[r0 + i], R = Rf[r0 + i];      // uniform -> s_load
        acc[i].x += L * T0.x + R * TN.x;
        acc[i].y += L * T0.y + R * TN.y;
    }

    #pragma unroll
    for (int i = 0; i < VR; ++i)
        buf_store_x2(acc[i], srdO, voffS, (r0 + i) * (IMW * 4), 0);
}

// ---------------------------------------------------------------------------
extern "C" void kernel_launch(void* const* d_in, const int* in_sizes, int n_in,
                              void* d_out, int out_size, void* d_ws, size_t ws_size,
                              hipStream_t stream) {
    const float* x     = (const float*)d_in[0];
    const float* sigma = (const float*)d_in[1];
    float* out = (float*)d_out;

    // ws: taps/L/R fp32 [0,4608) bytes, fp16 band tables [4608,14848),
    // fp16 tmp at byte 16384.
    float* ws_f = (float*)d_ws;
    unsigned short* tmpb = (unsigned short*)((char*)d_ws + 16384);

    weights_kernel<<<1, 128, 0, stream>>>(sigma, ws_f);
    hblur_mfma<<<(NROWS / 128) * (IMW / 64), 256, 0, stream>>>(x, ws_f, tmpb);
    vblur<<<NPLANES * (IMH / VR) * 2, 128, 0, stream>>>(tmpb, ws_f, out);
}

// Round 2
// 101.532 us; speedup vs baseline: 1.2087x; 1.1368x over previous
//
#include <hip/hip_runtime.h>

#define KSZ   121
#define KMEAN 60
#define IMW   512
#define IMH   512
#define NPLANES 24            // 8 * 3
#define NROWS (NPLANES * IMH) // 12288 independent image rows

typedef float    f32x4 __attribute__((ext_vector_type(4)));
typedef float    f32x2 __attribute__((ext_vector_type(2)));
typedef int      i32x4 __attribute__((ext_vector_type(4)));
typedef _Float16 f16x8 __attribute__((ext_vector_type(8)));
typedef _Float16 f16x2 __attribute__((ext_vector_type(2)));

// CK-style raw buffer intrinsics: HW bounds check returns 0 for OOB lanes.
__device__ unsigned short buf_load_u16(i32x4 srsrc, int voffset, int soffset, int aux)
    __asm("llvm.amdgcn.raw.buffer.load.i16");

// NOTE: SRD lives in SGPRs -> every input to make_srd MUST be wave-uniform.
__device__ __forceinline__ i32x4 make_srd(const void* p, int bytes) {
    union { const void* p; unsigned u[2]; } a; a.p = p;
    i32x4 r;
    r.x = (int)__builtin_amdgcn_readfirstlane((int)a.u[0]);   // wave-uniform base
    r.y = (int)__builtin_amdgcn_readfirstlane((int)a.u[1]);
    r.z = bytes;          // num_records: OOB load -> 0, OOB store -> dropped
    r.w = 0x00020000;     // raw dword SRD word3 (gfx9/gfx950)
    return r;
}

// ---------------------------------------------------------------------------
// ws layout (bytes):
//   [    0,  512)  taps w[0..120] fp32 (pad to 128 with 0)
//   [  512, 2560)  L[512] fp32   (float idx 128..640)
//   [ 2560, 4608)  R[512] fp32   (float idx 640..1152)
//   [ 4608,14848)  10 MFMA weight-band tables, fp16, fragment order:
//                    T[tt][lane][j], tt = tau+1, tau in [-1,8]
//                    value = w[16*tau + kk - ci - 4], kk = 8*(lane>>4)+j,
//                    ci = lane&15; 0 outside [0,120].
//   [16384, ... )  fp16 tmp (h-blurred), 24 planes * 512*512 * 2B
//
// Banded-matmul identity shared by BOTH passes (w-idx = 16(2s-n)+kk-ci-4):
//   h-pass:  A = x rows      (i=out-row),  B = table (j=out-col), tau = 2s-n
//   v-pass:  A = table       (i=out-row),  B = tmp   (j=out-col), tau = 2s-n
// Round-1 pass proves the A/B slot conventions match (same kk = 8g+j build).
// ---------------------------------------------------------------------------
__global__ __launch_bounds__(128) void weights_kernel(const float* __restrict__ sigma,
                                                      float* __restrict__ ws) {
    __shared__ float w[121];
    __shared__ float P[121];
    int t = threadIdx.x;
    float s = sigma[0] * 8.0f + 16.0f;
    float ninv = -1.0f / (2.0f * s * s);
    if (t < 121) { float d = (float)(t - KMEAN); w[t] = __expf(d * d * ninv); }
    __syncthreads();
    if (t == 0) {
        float sum = 0.f;
        for (int i = 0; i < 121; ++i) sum += w[i];
        float inv = 1.f / sum, run = 0.f;
        for (int i = 0; i < 121; ++i) { float wi = w[i] * inv; w[i] = wi; run += wi; P[i] = run; }
    }
    __syncthreads();
    ws[t] = (t < 121) ? w[t] : 0.f;                       // taps, 121..127 = 0
    #pragma unroll
    for (int j = 0; j < 4; ++j) {
        int o = t * 4 + j;
        ws[128 + o] = (o <= 59)  ? P[59 - o]          : 0.f;   // L
        ws[640 + o] = (o >= 452) ? (1.f - P[571 - o]) : 0.f;   // R
    }
    // MFMA band tables (fp16, fragment order). 10 tables x 512 entries.
    _Float16* tab = (_Float16*)((char*)ws + 4608);
    #pragma unroll
    for (int tt = 0; tt < 10; ++tt) {
        for (int e = t; e < 512; e += 128) {
            int lane = e >> 3, j = e & 7;
            int kk = ((lane >> 4) << 3) + j;   // slot->k convention (shared A/B)
            int ci = lane & 15;
            int wi = 16 * (tt - 1) + kk - ci - 4;
            float v = (wi >= 0 && wi <= 120) ? w[wi] : 0.f;
            tab[tt * 512 + e] = (_Float16)v;
        }
    }
}

// ---------------------------------------------------------------------------
// Kernel 2: horizontal pass as banded f16 MFMA (unchanged from round 1).
// ---------------------------------------------------------------------------
__global__ __launch_bounds__(256) void hblur_mfma(const float* __restrict__ x,
                                                  const float* __restrict__ ws,
                                                  unsigned short* __restrict__ tmpb) {
    // XCD-aware swizzle: 768 blocks % 8 == 0; consecutive swz share x-windows.
    const int bid = blockIdx.x;
    const int swz = (bid & 7) * 96 + (bid >> 3);
    const int br = swz >> 3;                 // 0..95  row-block
    const int bc = swz & 7;                  // 0..7   col-tile
    const int tid  = threadIdx.x;
    const int lane = tid & 63;
    const int g    = lane >> 4;              // k-block / D-row group
    const int ci   = lane & 15;              // A row within tile / D col
    const int R0   = br * 128 + (tid >> 6) * 32;
    const int c0   = bc * 64;

    // preload the 10 band tables (wave-uniform B fragments)
    const _Float16* __restrict__ tab = (const _Float16*)((const char*)ws + 4608);
    f16x8 T[10];
    #pragma unroll
    for (int tt = 0; tt < 10; ++tt)
        T[tt] = ((const f16x8*)(tab + tt * 512))[lane];

    f32x4 acc[2][4];
    #pragma unroll
    for (int q = 0; q < 2; ++q)
        #pragma unroll
        for (int n = 0; n < 4; ++n)
            acc[q][n] = (f32x4){0.f, 0.f, 0.f, 0.f};

    const float* __restrict__ xr0 = x + (size_t)(R0 + ci) * IMW;        // q=0 row
    const float* __restrict__ xr1 = x + (size_t)(R0 + 16 + ci) * IMW;   // q=1 row

    #pragma unroll
    for (int s = 0; s < 6; ++s) {
        const int colbase = c0 - 64 + 32 * s;
        if ((unsigned)colbase < 512u) {      // 32-aligned step: all-in or all-out
            const int co = colbase + 8 * g;
            f32x4 u0 = *(const f32x4*)(xr0 + co);
            f32x4 u1 = *(const f32x4*)(xr0 + co + 4);
            f32x4 v0 = *(const f32x4*)(xr1 + co);
            f32x4 v1 = *(const f32x4*)(xr1 + co + 4);
            f16x8 A0, A1;
            A0[0]=(_Float16)u0.x; A0[1]=(_Float16)u0.y; A0[2]=(_Float16)u0.z; A0[3]=(_Float16)u0.w;
            A0[4]=(_Float16)u1.x; A0[5]=(_Float16)u1.y; A0[6]=(_Float16)u1.z; A0[7]=(_Float16)u1.w;
            A1[0]=(_Float16)v0.x; A1[1]=(_Float16)v0.y; A1[2]=(_Float16)v0.z; A1[3]=(_Float16)v0.w;
            A1[4]=(_Float16)v1.x; A1[5]=(_Float16)v1.y; A1[6]=(_Float16)v1.z; A1[7]=(_Float16)v1.w;
            #pragma unroll
            for (int n = 0; n < 4; ++n) {
                const int tt = 2 * s - n + 1;          // tau+1, compile-time
                if (tt >= 0 && tt < 10) {
                    acc[0][n] = __builtin_amdgcn_mfma_f32_16x16x32_f16(A0, T[tt], acc[0][n], 0, 0, 0);
                    acc[1][n] = __builtin_amdgcn_mfma_f32_16x16x32_f16(A1, T[tt], acc[1][n], 0, 0, 0);
                }
            }
        }
    }

    // replicate-pad corrections, only the two edge col-tiles have nonzero L/R
    if (c0 == 0 || c0 == 448) {
        const float* __restrict__ Lf = ws + 128;
        const float* __restrict__ Rf = ws + 640;
        float Lc[4], Rc[4];
        #pragma unroll
        for (int n = 0; n < 4; ++n) {
            Lc[n] = Lf[c0 + 16 * n + ci];
            Rc[n] = Rf[c0 + 16 * n + ci];
        }
        #pragma unroll
        for (int q = 0; q < 2; ++q) {
            #pragma unroll
            for (int r = 0; r < 4; ++r) {
                const int row = R0 + 16 * q + 4 * g + r;   // D row = 4*(lane>>4)+reg
                const float x0 = x[(size_t)row * IMW];
                const float xN = x[(size_t)row * IMW + IMW - 1];
                #pragma unroll
                for (int n = 0; n < 4; ++n)
                    acc[q][n][r] += x0 * Lc[n] + xN * Rc[n];
            }
        }
    }

    // store fp16 tmp: D layout col = lane&15, row = 4*(lane>>4)+reg (m89)
    _Float16* __restrict__ tp = (_Float16*)tmpb;
    #pragma unroll
    for (int q = 0; q < 2; ++q)
        #pragma unroll
        for (int r = 0; r < 4; ++r) {
            const size_t rowoff = (size_t)(R0 + 16 * q + 4 * g + r) * IMW;
            #pragma unroll
            for (int n = 0; n < 4; ++n)
                tp[rowoff + c0 + 16 * n + ci] = (_Float16)acc[q][n][r];
        }
}

// ---------------------------------------------------------------------------
// Kernel 3: vertical pass as banded f16 MFMA (was fp32 VALU, ~38 us).
//   out[r,c] = sum_k w[k-r+60]*tmp[k,c]  + L[r]*tmp[0,c] + R[r]*tmp[511,c]
// A = band tables (i = out-row-within-16 = lane&15, slots = k) -- SAME tables.
// B = tmp fragments (j = out-col = lane&15, slots = k): 8 u16 loads + 4 packs,
//     fp16 native (no cvt). Vertical zero-pad is branchless: OOB row soffsets
//     (negative wraps / >=512) fail the SRD bounds check -> HW returns 0.
// Wave tile: 64 rows (n=0..3) x 32 cols (m=0..1). Block = 4 waves = 64r x 128c.
// k-window [r0p-64, r0p+128), 6 steps of 32 (32-aligned since r0p % 64 == 0).
// Stores: fp32 dwords, 16 consecutive cols per 16-lane group = 4 x 64B
// segments per inst. One-step software pipeline (cur/nxt) on the u16 loads.
// ---------------------------------------------------------------------------
__global__ __launch_bounds__(256) void vblur_mfma(const unsigned short* __restrict__ tmpb,
                                                  const float* __restrict__ ws,
                                                  float* __restrict__ out) {
    const int bid = blockIdx.x;
    const int swz = (bid & 7) * 96 + (bid >> 3);   // 768 = 8 * 96, bijective
    const int rb  = swz >> 2;                      // 0..191: 64-row block
    const int cbw = swz & 3;                       // 0..3: 128-col block
    const int tid  = threadIdx.x;
    const int lane = tid & 63;
    const int wv   = tid >> 6;                     // wave -> 32-col tile
    const int g    = lane >> 4;
    const int ci   = lane & 15;
    const int plane = rb >> 3;
    const int r0p   = (rb & 7) * 64;               // row base within plane
    const int c0    = cbw * 128 + wv * 32;

    const unsigned short* __restrict__ tp = tmpb + (size_t)plane * (IMW * IMH);
    float* __restrict__ op = out + (size_t)plane * (IMW * IMH);
    const i32x4 srdT = make_srd(tp, IMW * IMH * 2);

    // preload the 10 band tables as A-operands (lane&15 = out-row, slots = k)
    const _Float16* __restrict__ tab = (const _Float16*)((const char*)ws + 4608);
    f16x8 T[10];
    #pragma unroll
    for (int tt = 0; tt < 10; ++tt)
        T[tt] = ((const f16x8*)(tab + tt * 512))[lane];

    f32x4 acc[4][2];
    #pragma unroll
    for (int n = 0; n < 4; ++n) {
        acc[n][0] = (f32x4){0.f, 0.f, 0.f, 0.f};
        acc[n][1] = (f32x4){0.f, 0.f, 0.f, 0.f};
    }

    // voffset: g-dependent row part (8g rows) + col within tile
    const int v0 = g * 8 * 1024 + (c0 + ci) * 2;       // m = 0
    const int v1 = v0 + 32;                            // m = 1 (+16 cols)

    // B-frag u16 loads, one-step pipeline. soffset = (kbase+j)*1024 is SALU
    // (blockIdx-derived); OOB rows -> bounds-check zero (vertical zero-pad).
#define VLOADSTEP(dst, S) do {                                              \
        const int kb_ = r0p - 64 + 32 * (S);                                \
        _Pragma("unroll")                                                   \
        for (int j_ = 0; j_ < 8; ++j_) {                                    \
            dst[0][j_] = buf_load_u16(srdT, v0, (kb_ + j_) * 1024, 0);      \
            dst[1][j_] = buf_load_u16(srdT, v1, (kb_ + j_) * 1024, 0);      \
        } } while (0)

    unsigned short cur[2][8], nxt[2][8];
    VLOADSTEP(cur, 0);

    union FragU { unsigned u[4]; f16x8 h; };

    #pragma unroll
    for (int s = 0; s < 6; ++s) {
        if (s < 5) VLOADSTEP(nxt, s + 1);
        FragU B0, B1;
        #pragma unroll
        for (int d = 0; d < 4; ++d) {
            B0.u[d] = (unsigned)cur[0][2 * d] | ((unsigned)cur[0][2 * d + 1] << 16);
            B1.u[d] = (unsigned)cur[1][2 * d] | ((unsigned)cur[1][2 * d + 1] << 16);
        }
        #pragma unroll
        for (int n = 0; n < 4; ++n) {
            const int tt = 2 * s - n + 1;              // tau+1, compile-time
            if (tt >= 0 && tt < 10) {
                acc[n][0] = __builtin_amdgcn_mfma_f32_16x16x32_f16(T[tt], B0.h, acc[n][0], 0, 0, 0);
                acc[n][1] = __builtin_amdgcn_mfma_f32_16x16x32_f16(T[tt], B1.h, acc[n][1], 0, 0, 0);
            }
        }
        if (s < 5) {
            #pragma unroll
            for (int m = 0; m < 2; ++m)
                #pragma unroll
                for (int j = 0; j < 8; ++j)
                    cur[m][j] = nxt[m][j];
        }
    }
#undef VLOADSTEP

    // replicate-pad corrections: rows 0/511 of tmp, weights L[r]/R[r]
    if (r0p == 0 || r0p == 448) {
        const float* __restrict__ Lf = ws + 128;
        const float* __restrict__ Rf = ws + 640;
        const int vc0 = (c0 + ci) * 2;                 // col-only voffset
        union { unsigned short u; _Float16 h; } cv;
        float t0[2], tN[2];
        #pragma unroll
        for (int m = 0; m < 2; ++m) {
            cv.u = buf_load_u16(srdT, vc0 + 32 * m, 0, 0);                 t0[m] = (float)cv.h;
            cv.u = buf_load_u16(srdT, vc0 + 32 * m, (IMH - 1) * 1024, 0);  tN[m] = (float)cv.h;
        }
        #pragma unroll
        for (int n = 0; n < 4; ++n)
            #pragma unroll
            for (int r = 0; r < 4; ++r) {
                const int row = r0p + 16 * n + 4 * g + r;   // D row = 4g+reg
                const float L = Lf[row], R = Rf[row];
                acc[n][0][r] += L * t0[0] + R * tN[0];
                acc[n][1][r] += L * t0[1] + R * tN[1];
            }
    }

    // store fp32: D col = lane&15 (out col), D row = 4g+reg (out row)
    #pragma unroll
    for (int n = 0; n < 4; ++n)
        #pragma unroll
        for (int r = 0; r < 4; ++r) {
            const size_t ro = (size_t)(r0p + 16 * n + 4 * g + r) * IMW;
            op[ro + c0 + ci]      = acc[n][0][r];
            op[ro + c0 + 16 + ci] = acc[n][1][r];
        }
}

// ---------------------------------------------------------------------------
extern "C" void kernel_launch(void* const* d_in, const int* in_sizes, int n_in,
                              void* d_out, int out_size, void* d_ws, size_t ws_size,
                              hipStream_t stream) {
    const float* x     = (const float*)d_in[0];
    const float* sigma = (const float*)d_in[1];
    float* out = (float*)d_out;

    // ws: taps/L/R fp32 [0,4608) bytes, fp16 band tables [4608,14848),
    // fp16 tmp at byte 16384.
    float* ws_f = (float*)d_ws;
    unsigned short* tmpb = (unsigned short*)((char*)d_ws + 16384);

    weights_kernel<<<1, 128, 0, stream>>>(sigma, ws_f);
    hblur_mfma<<<(NROWS / 128) * (IMW / 64), 256, 0, stream>>>(x, ws_f, tmpb);
    vblur_mfma<<<(NROWS / 64) * (IMW / 128), 256, 0, stream>>>(tmpb, ws_f, out);
}